// Round 7
// baseline (1797.526 us; speedup 1.0000x reference)
//
#include <hip/hip_runtime.h>
#include <hip/hip_bf16.h>
#include <math.h>

#define DIM 768
#define NHEADS 12
#define HD 64
#define SEQ 4096

typedef __bf16 bf16x8 __attribute__((ext_vector_type(8)));
typedef float f32x4 __attribute__((ext_vector_type(4)));

__device__ inline ushort f2bf(float f) {
    union { float f; uint u; } v; v.f = f;
    uint r = v.u + 0x7FFF + ((v.u >> 16) & 1);   // RNE
    return (ushort)(r >> 16);
}

// ---------------------------------------------------------------------------
// QKV GEMM: C[4096,2304] = x[4096,768] @ qkv_w[2304,768]^T, f32 in,
// bf16 MFMA inside, f32 result scattered to QKV [3][NHEADS][SEQ][HD].
// (Validated numerically == pure-fp32 vgemm by rounds 3<->4 cross-check.)
// ---------------------------------------------------------------------------
__global__ __launch_bounds__(256)
void gemm_qkv(const float* __restrict__ A, const float* __restrict__ B,
              float* __restrict__ qkv_out)
{
    constexpr int BM = 128, BN = 128, BK = 64, PAD = 8;
    __shared__ ushort Ah[BM][BK + PAD];
    __shared__ ushort Bh[BN][BK + PAD];

    const int t    = threadIdx.x;
    const int lane = t & 63;
    const int wv   = t >> 6;
    const int wm   = (wv >> 1) * 64;
    const int wn   = (wv & 1) * 64;
    const int m0   = blockIdx.y * BM;
    const int n0   = blockIdx.x * BN;

    f32x4 acc[4][4] = {};

    const int lrow = t >> 4;         // 0..15
    const int lcol = (t & 15) * 4;   // 0..60 step 4

    for (int k0 = 0; k0 < DIM; k0 += BK) {
        #pragma unroll
        for (int i = 0; i < 8; ++i) {
            const int row = lrow + i * 16;
            float4 a4 = *(const float4*)&A[(size_t)(m0 + row) * DIM + k0 + lcol];
            float4 b4 = *(const float4*)&B[(size_t)(n0 + row) * DIM + k0 + lcol];
            ushort4 ah, bh;
            ah.x = f2bf(a4.x); ah.y = f2bf(a4.y);
            ah.z = f2bf(a4.z); ah.w = f2bf(a4.w);
            bh.x = f2bf(b4.x); bh.y = f2bf(b4.y);
            bh.z = f2bf(b4.z); bh.w = f2bf(b4.w);
            *(ushort4*)&Ah[row][lcol] = ah;
            *(ushort4*)&Bh[row][lcol] = bh;
        }
        __syncthreads();

        #pragma unroll
        for (int ks = 0; ks < BK; ks += 32) {
            const int koff = ks + ((lane >> 4) << 3);
            const int rsel = lane & 15;
            bf16x8 af[4], bf[4];
            #pragma unroll
            for (int i = 0; i < 4; ++i) {
                af[i] = *(const bf16x8*)&Ah[wm + i * 16 + rsel][koff];
                bf[i] = *(const bf16x8*)&Bh[wn + i * 16 + rsel][koff];
            }
            #pragma unroll
            for (int i = 0; i < 4; ++i)
                #pragma unroll
                for (int j = 0; j < 4; ++j)
                    acc[i][j] = __builtin_amdgcn_mfma_f32_16x16x32_bf16(
                        af[i], bf[j], acc[i][j], 0, 0, 0);
        }
        __syncthreads();
    }

    // C/D layout: col = lane&15, row = (lane>>4)*4 + r
    const int rbase = m0 + wm + ((lane >> 4) << 2);
    const int cbase = n0 + wn + (lane & 15);

    #pragma unroll
    for (int j = 0; j < 4; ++j) {
        const int col = cbase + j * 16;
        const int tt  = col / DIM;
        const int rem = col % DIM;
        const int h   = rem >> 6;
        const int d   = rem & 63;
        float* dst = qkv_out + (size_t)(tt * NHEADS + h) * SEQ * HD + d;
        #pragma unroll
        for (int i = 0; i < 4; ++i) {
            const int row0 = rbase + i * 16;
            #pragma unroll
            for (int r = 0; r < 4; ++r)
                dst[(size_t)(row0 + r) * HD] = acc[i][j][r];
        }
    }
}

// ---------------------------------------------------------------------------
// RoPE in-place on q,k sections of fp32 QKV [3][H][N][D].
// ---------------------------------------------------------------------------
__global__ __launch_bounds__(256)
void rope_kernel(float* __restrict__ QKV)
{
    const int idx = blockIdx.x * 256 + threadIdx.x;   // 12*4096*32
    const int j = idx & 31;
    const int n = (idx >> 5) & (SEQ - 1);
    const int h = idx >> 17;
    if (h >= NHEADS) return;

    const float invf = (float)pow(10000.0, -(double)j / 32.0);
    const float ang  = (float)n * invf;               // f32, matches ref freqs
    double s, c;
    sincos((double)ang, &s, &c);
    const float cf = (float)c, sf = (float)s;

    const size_t base = ((size_t)h * SEQ + n) * HD;
    float* qp = QKV + base;
    float* kp = QKV + (size_t)NHEADS * SEQ * HD + base;

    float a = qp[j], b = qp[j + 32];
    qp[j]      = a * cf - b * sf;
    qp[j + 32] = b * cf + a * sf;
    a = kp[j];  b = kp[j + 32];
    kp[j]      = a * cf - b * sf;
    kp[j + 32] = b * cf + a * sf;
}

// ---------------------------------------------------------------------------
// Flash attention, fp32 vector math. 256 thr = 64 q-rows x 4 D-parts.
// Writes bf16 attnout [SEQ][DIM]. (Validated == exact two-pass softmax.)
// ---------------------------------------------------------------------------
__global__ __launch_bounds__(256)
void flash_fp32(const float* __restrict__ QKV, ushort* __restrict__ AO)
{
    __shared__ float Ks[64][64];
    __shared__ float Vs[64][64];

    const int t  = threadIdx.x;
    const int r  = t >> 2;
    const int p  = t & 3;
    const int h  = blockIdx.y;
    const int q0 = blockIdx.x * 64;

    const float* qptr = QKV + ((size_t)h * SEQ + q0 + r) * HD + p * 16;
    float q[16], o[16];
    #pragma unroll
    for (int i = 0; i < 16; i += 4) {
        float4 v4 = *(const float4*)&qptr[i];
        q[i] = v4.x; q[i+1] = v4.y; q[i+2] = v4.z; q[i+3] = v4.w;
    }
    #pragma unroll
    for (int i = 0; i < 16; ++i) o[i] = 0.f;
    float m = -INFINITY, l = 0.f;

    const float* kbase = QKV + (size_t)(NHEADS + h) * SEQ * HD;
    const float* vbase = QKV + (size_t)(2 * NHEADS + h) * SEQ * HD;

    for (int k0 = 0; k0 < SEQ; k0 += 64) {
        #pragma unroll
        for (int i = 0; i < 4; ++i) {
            int lin = i * 256 + t;
            int row = lin >> 4;
            int seg = (lin & 15) * 4;
            *(float4*)&Ks[row][seg] = *(const float4*)&kbase[(size_t)(k0 + row) * HD + seg];
            *(float4*)&Vs[row][seg] = *(const float4*)&vbase[(size_t)(k0 + row) * HD + seg];
        }
        __syncthreads();

        for (int kk = 0; kk < 64; ++kk) {
            float part = 0.f;
            #pragma unroll
            for (int j = 0; j < 16; ++j) part += q[j] * Ks[kk][p * 16 + j];
            part += __shfl_xor(part, 1, 64);
            part += __shfl_xor(part, 2, 64);
            const float logit = part * 0.125f;
            const float mn = fmaxf(m, logit);
            const float cs = __expf(m - mn);
            const float pe = __expf(logit - mn);
            l = l * cs + pe;
            m = mn;
            #pragma unroll
            for (int j = 0; j < 16; ++j)
                o[j] = o[j] * cs + pe * Vs[kk][p * 16 + j];
        }
        __syncthreads();
    }

    const float inv = 1.f / l;
    ushort* dst = AO + (size_t)(q0 + r) * DIM + h * HD + p * 16;
    #pragma unroll
    for (int j = 0; j < 16; ++j) dst[j] = f2bf(o[j] * inv);
}

// ---------------------------------------------------------------------------
// Proj GEMM: out[4096,768] = attnout(bf16) @ proj_w(f32->bf16)^T + proj_b,
// *** FP32 OUTPUT *** (the reference's output dtype is float32 — writing
// bf16 here was the structural bug behind rounds 2-6's constant 0.2246).
// ---------------------------------------------------------------------------
__global__ __launch_bounds__(256)
void gemm_proj(const ushort* __restrict__ A, const float* __restrict__ B,
               const float* __restrict__ bias, float* __restrict__ out)
{
    constexpr int BM = 128, BN = 128, BK = 64, PAD = 8;
    __shared__ ushort As[BM][BK + PAD];
    __shared__ ushort Bs[BN][BK + PAD];

    const int t    = threadIdx.x;
    const int lane = t & 63;
    const int wv   = t >> 6;
    const int wm   = (wv >> 1) * 64;
    const int wn   = (wv & 1) * 64;
    const int m0   = blockIdx.y * BM;
    const int n0   = blockIdx.x * BN;

    f32x4 acc[4][4] = {};

    const int arow = t >> 3;          // 0..31
    const int aseg = (t & 7) * 8;     // bf16 16B chunks
    const int brow = t >> 4;          // 0..15
    const int bcol = (t & 15) * 4;    // f32 16B chunks

    for (int k0 = 0; k0 < DIM; k0 += BK) {
        #pragma unroll
        for (int i = 0; i < 4; ++i) {
            const int row = arow + i * 32;
            *(float4*)&As[row][aseg] =
                *(const float4*)&A[(size_t)(m0 + row) * DIM + k0 + aseg];
        }
        #pragma unroll
        for (int i = 0; i < 8; ++i) {
            const int row = brow + i * 16;
            float4 b4 = *(const float4*)&B[(size_t)(n0 + row) * DIM + k0 + bcol];
            ushort4 bh;
            bh.x = f2bf(b4.x); bh.y = f2bf(b4.y);
            bh.z = f2bf(b4.z); bh.w = f2bf(b4.w);
            *(ushort4*)&Bs[row][bcol] = bh;
        }
        __syncthreads();

        #pragma unroll
        for (int ks = 0; ks < BK; ks += 32) {
            const int koff = ks + ((lane >> 4) << 3);
            const int rsel = lane & 15;
            bf16x8 af[4], bf[4];
            #pragma unroll
            for (int i = 0; i < 4; ++i) {
                af[i] = *(const bf16x8*)&As[wm + i * 16 + rsel][koff];
                bf[i] = *(const bf16x8*)&Bs[wn + i * 16 + rsel][koff];
            }
            #pragma unroll
            for (int i = 0; i < 4; ++i)
                #pragma unroll
                for (int j = 0; j < 4; ++j)
                    acc[i][j] = __builtin_amdgcn_mfma_f32_16x16x32_bf16(
                        af[i], bf[j], acc[i][j], 0, 0, 0);
        }
        __syncthreads();
    }

    const int rbase = m0 + wm + ((lane >> 4) << 2);
    const int cbase = n0 + wn + (lane & 15);

    #pragma unroll
    for (int j = 0; j < 4; ++j) {
        const int col = cbase + j * 16;
        const float bv = bias[col];
        #pragma unroll
        for (int i = 0; i < 4; ++i) {
            const int row0 = rbase + i * 16;
            #pragma unroll
            for (int r = 0; r < 4; ++r)
                out[(size_t)(row0 + r) * DIM + col] = acc[i][j][r] + bv;  // f32!
        }
    }
}

// ---------------------------------------------------------------------------
extern "C" void kernel_launch(void* const* d_in, const int* in_sizes, int n_in,
                              void* d_out, int out_size, void* d_ws, size_t ws_size,
                              hipStream_t stream)
{
    const float* x      = (const float*)d_in[0];   // [4096][768] f32
    const float* qkv_w  = (const float*)d_in[1];   // [2304][768] f32
    const float* proj_w = (const float*)d_in[2];   // [768][768]  f32
    const float* proj_b = (const float*)d_in[3];   // [768]       f32

    float* qkv = (float*)d_ws;                     // [3][12][4096][64] f32 (36 MB)
    ushort* attnout =
        (ushort*)((char*)d_ws + (size_t)3 * NHEADS * SEQ * HD * sizeof(float));
    float* out = (float*)d_out;                    // *** f32 [4096][768] ***

    gemm_qkv<<<dim3(3 * DIM / 128, SEQ / 128), 256, 0, stream>>>(x, qkv_w, qkv);

    rope_kernel<<<(NHEADS * SEQ * 32) / 256, 256, 0, stream>>>(qkv);

    flash_fp32<<<dim3(SEQ / 64, NHEADS), 256, 0, stream>>>(qkv, attnout);

    gemm_proj<<<dim3(DIM / 128, SEQ / 128), 256, 0, stream>>>(
        attnout, proj_w, proj_b, out);
}

// Round 8
// 480.082 us; speedup vs baseline: 3.7442x; 3.7442x over previous
//
#include <hip/hip_runtime.h>
#include <hip/hip_bf16.h>
#include <math.h>

#define DIM 768
#define NHEADS 12
#define HD 64
#define SEQ 4096

typedef __bf16 bf16x8 __attribute__((ext_vector_type(8)));
typedef float f32x4 __attribute__((ext_vector_type(4)));

__device__ inline ushort f2bf(float f) {
    union { float f; uint u; } v; v.f = f;
    uint r = v.u + 0x7FFF + ((v.u >> 16) & 1);   // RNE
    return (ushort)(r >> 16);
}

// ---------------------------------------------------------------------------
// QKV GEMM + fused RoPE + layout: C[4096,2304] = x @ qkv_w^T (bf16 MFMA).
// Epilogue: each wave's 64-col span == exactly one (t,h) head slice.
//   t=0 (q): RoPE pairs (d, d+32), then *0.125 (exact pow2), bf16 -> Qb[h][n][d]
//   t=1 (k): RoPE, bf16 -> Kb[h][n][d]
//   t=2 (v): bf16 -> Vt[h][d][n]  (transposed for PV MFMA B-fragments)
// ---------------------------------------------------------------------------
__global__ __launch_bounds__(256)
void gemm_qkv(const float* __restrict__ A, const float* __restrict__ B,
              ushort* __restrict__ Qb, ushort* __restrict__ Kb,
              ushort* __restrict__ Vt)
{
    constexpr int BM = 128, BN = 128, BK = 64, PAD = 8;
    __shared__ ushort Ah[BM][BK + PAD];
    __shared__ ushort Bh[BN][BK + PAD];

    const int t    = threadIdx.x;
    const int lane = t & 63;
    const int wv   = t >> 6;
    const int wm   = (wv >> 1) * 64;
    const int wn   = (wv & 1) * 64;
    const int m0   = blockIdx.y * BM;
    const int n0   = blockIdx.x * BN;

    f32x4 acc[4][4] = {};

    const int lrow = t >> 4;         // 0..15
    const int lcol = (t & 15) * 4;   // 0..60 step 4

    for (int k0 = 0; k0 < DIM; k0 += BK) {
        #pragma unroll
        for (int i = 0; i < 8; ++i) {
            const int row = lrow + i * 16;
            float4 a4 = *(const float4*)&A[(size_t)(m0 + row) * DIM + k0 + lcol];
            float4 b4 = *(const float4*)&B[(size_t)(n0 + row) * DIM + k0 + lcol];
            ushort4 ah, bh;
            ah.x = f2bf(a4.x); ah.y = f2bf(a4.y);
            ah.z = f2bf(a4.z); ah.w = f2bf(a4.w);
            bh.x = f2bf(b4.x); bh.y = f2bf(b4.y);
            bh.z = f2bf(b4.z); bh.w = f2bf(b4.w);
            *(ushort4*)&Ah[row][lcol] = ah;
            *(ushort4*)&Bh[row][lcol] = bh;
        }
        __syncthreads();

        #pragma unroll
        for (int ks = 0; ks < BK; ks += 32) {
            const int koff = ks + ((lane >> 4) << 3);
            const int rsel = lane & 15;
            bf16x8 af[4], bf[4];
            #pragma unroll
            for (int i = 0; i < 4; ++i) {
                af[i] = *(const bf16x8*)&Ah[wm + i * 16 + rsel][koff];
                bf[i] = *(const bf16x8*)&Bh[wn + i * 16 + rsel][koff];
            }
            #pragma unroll
            for (int i = 0; i < 4; ++i)
                #pragma unroll
                for (int j = 0; j < 4; ++j)
                    acc[i][j] = __builtin_amdgcn_mfma_f32_16x16x32_bf16(
                        af[i], bf[j], acc[i][j], 0, 0, 0);
        }
        __syncthreads();
    }

    // C/D layout: col = cbase + 16j (cbase = wave col origin + rsel),
    //             row = rbase + 16i + r (rbase = wave row origin + 4*quad)
    const int rsel  = lane & 15;
    const int quad  = lane >> 4;
    const int rbase = m0 + wm + (quad << 2);
    const int c0    = n0 + wn;          // 64-aligned -> single (t,h) per wave
    const int tt    = c0 / DIM;
    const int h     = (c0 % DIM) >> 6;

    if (tt == 2) {
        // V: pack 4 consecutive n per store -> Vt[h][d][n]
        #pragma unroll
        for (int j = 0; j < 4; ++j) {
            const int d = rsel + 16 * j;
            #pragma unroll
            for (int i = 0; i < 4; ++i) {
                const int nr = rbase + i * 16;
                ushort4 w;
                w.x = f2bf(acc[i][j][0]); w.y = f2bf(acc[i][j][1]);
                w.z = f2bf(acc[i][j][2]); w.w = f2bf(acc[i][j][3]);
                *(ushort4*)&Vt[((size_t)h * HD + d) * SEQ + nr] = w;
            }
        }
    } else {
        ushort* dstb = (tt == 0 ? Qb : Kb) + (size_t)h * SEQ * HD;
        const float qs = (tt == 0) ? 0.125f : 1.0f;   // HD^-0.5, exact pow2
        const float if0 = (float)pow(10000.0, -(double)rsel / 32.0);
        const float if1 = (float)pow(10000.0, -(double)(rsel + 16) / 32.0);
        #pragma unroll
        for (int i = 0; i < 4; ++i)
            #pragma unroll
            for (int r = 0; r < 4; ++r) {
                const int n = rbase + i * 16 + r;
                #pragma unroll
                for (int j = 0; j < 2; ++j) {
                    const float a = acc[i][j][r];
                    const float b = acc[i][j + 2][r];
                    const float ang = (float)n * (j ? if1 : if0);
                    float s, c;
                    __sincosf(ang, &s, &c);
                    dstb[(size_t)n * HD + rsel + 16 * j]      = f2bf((a * c - b * s) * qs);
                    dstb[(size_t)n * HD + rsel + 16 * j + 32] = f2bf((b * c + a * s) * qs);
                }
            }
    }
}

// ---------------------------------------------------------------------------
// MFMA flash attention. Block = 256 thr = 4 waves; each wave owns 16 q-rows.
// Grid (SEQ/64, NHEADS) = 768 blocks. Per 64-key tile:
//   S = Q*K^T via 8 MFMA (frags loaded directly from global, 16B/lane),
//   online softmax (4 rows/lane, shfl_xor reduce), P -> wave-private LDS
//   (C/D->A layout transform), P*V via 8 MFMA with V frags from Vt[h][d][n].
// O accumulated in C/D layout, normalized, written bf16 [SEQ][DIM].
// ---------------------------------------------------------------------------
__global__ __launch_bounds__(256)
void flash_mfma(const ushort* __restrict__ Qb, const ushort* __restrict__ Kb,
                const ushort* __restrict__ Vt, ushort* __restrict__ AO)
{
    __shared__ ushort Pl[4][16][72];   // per-wave P tile, padded (144B rows)

    const int t    = threadIdx.x;
    const int lane = t & 63;
    const int wv   = t >> 6;
    const int rsel = lane & 15;
    const int quad = lane >> 4;
    const int h    = blockIdx.y;
    const int q0   = blockIdx.x * 64 + wv * 16;

    // Q A-frags (persistent): A[m=rsel][k=quad*8+jj], ks = 32-wide k-step
    bf16x8 aq[2];
    #pragma unroll
    for (int ks = 0; ks < 2; ++ks)
        aq[ks] = *(const bf16x8*)&Qb[((size_t)h * SEQ + q0 + rsel) * HD
                                     + ks * 32 + quad * 8];

    f32x4 accO[4] = {};
    float mrow[4] = {-INFINITY, -INFINITY, -INFINITY, -INFINITY};
    float lrow[4] = {};

    for (int k0 = 0; k0 < SEQ; k0 += 64) {
        // K B-frags: B[n=key=rsel][k=d]
        bf16x8 bk[4][2];
        #pragma unroll
        for (int n = 0; n < 4; ++n)
            #pragma unroll
            for (int ks = 0; ks < 2; ++ks)
                bk[n][ks] = *(const bf16x8*)&Kb[((size_t)h * SEQ + k0 + n * 16 + rsel) * HD
                                                + ks * 32 + quad * 8];
        f32x4 accS[4] = {};
        #pragma unroll
        for (int ks = 0; ks < 2; ++ks)
            #pragma unroll
            for (int n = 0; n < 4; ++n)
                accS[n] = __builtin_amdgcn_mfma_f32_16x16x32_bf16(
                    aq[ks], bk[n][ks], accS[n], 0, 0, 0);

        // online softmax; lane's rows: 4*quad + r; lane's keys: 16n + rsel
        float cs[4];
        #pragma unroll
        for (int r = 0; r < 4; ++r) {
            float mx = fmaxf(fmaxf(accS[0][r], accS[1][r]),
                             fmaxf(accS[2][r], accS[3][r]));
            mx = fmaxf(mx, __shfl_xor(mx, 1));
            mx = fmaxf(mx, __shfl_xor(mx, 2));
            mx = fmaxf(mx, __shfl_xor(mx, 4));
            mx = fmaxf(mx, __shfl_xor(mx, 8));
            const float mn = fmaxf(mrow[r], mx);
            cs[r] = __expf(mrow[r] - mn);       // first tile: exp(-inf)=0
            mrow[r] = mn;
            float p0 = __expf(accS[0][r] - mn);
            float p1 = __expf(accS[1][r] - mn);
            float p2 = __expf(accS[2][r] - mn);
            float p3 = __expf(accS[3][r] - mn);
            Pl[wv][quad * 4 + r][rsel]      = f2bf(p0);
            Pl[wv][quad * 4 + r][16 + rsel] = f2bf(p1);
            Pl[wv][quad * 4 + r][32 + rsel] = f2bf(p2);
            Pl[wv][quad * 4 + r][48 + rsel] = f2bf(p3);
            float rs = p0 + p1 + p2 + p3;
            rs += __shfl_xor(rs, 1);
            rs += __shfl_xor(rs, 2);
            rs += __shfl_xor(rs, 4);
            rs += __shfl_xor(rs, 8);
            lrow[r] = lrow[r] * cs[r] + rs;
        }
        // rescale O
        #pragma unroll
        for (int j = 0; j < 4; ++j)
            #pragma unroll
            for (int r = 0; r < 4; ++r)
                accO[j][r] *= cs[r];

        // wave-private LDS: enforce write->read ordering without a barrier
        asm volatile("s_waitcnt lgkmcnt(0)" ::: "memory");

        // P A-frags: A[m=rsel][k=key]
        bf16x8 ap[2];
        #pragma unroll
        for (int ks = 0; ks < 2; ++ks)
            ap[ks] = *(const bf16x8*)&Pl[wv][rsel][ks * 32 + quad * 8];
        // V B-frags: B[n=d=rsel][k=key] from Vt[h][d][n]
        bf16x8 bv[4][2];
        #pragma unroll
        for (int j = 0; j < 4; ++j)
            #pragma unroll
            for (int ks = 0; ks < 2; ++ks)
                bv[j][ks] = *(const bf16x8*)&Vt[((size_t)h * HD + j * 16 + rsel) * SEQ
                                                + k0 + ks * 32 + quad * 8];
        #pragma unroll
        for (int ks = 0; ks < 2; ++ks)
            #pragma unroll
            for (int j = 0; j < 4; ++j)
                accO[j] = __builtin_amdgcn_mfma_f32_16x16x32_bf16(
                    ap[ks], bv[j][ks], accO[j], 0, 0, 0);
    }

    #pragma unroll
    for (int r = 0; r < 4; ++r) {
        const float inv = 1.0f / lrow[r];
        const int n = q0 + quad * 4 + r;
        #pragma unroll
        for (int j = 0; j < 4; ++j)
            AO[(size_t)n * DIM + h * HD + j * 16 + rsel] = f2bf(accO[j][r] * inv);
    }
}

// ---------------------------------------------------------------------------
// Proj GEMM: out[4096,768] = attnout(bf16) @ proj_w(f32->bf16)^T + proj_b,
// fp32 output (reference output dtype).
// ---------------------------------------------------------------------------
__global__ __launch_bounds__(256)
void gemm_proj(const ushort* __restrict__ A, const float* __restrict__ B,
               const float* __restrict__ bias, float* __restrict__ out)
{
    constexpr int BM = 128, BN = 128, BK = 64, PAD = 8;
    __shared__ ushort As[BM][BK + PAD];
    __shared__ ushort Bs[BN][BK + PAD];

    const int t    = threadIdx.x;
    const int lane = t & 63;
    const int wv   = t >> 6;
    const int wm   = (wv >> 1) * 64;
    const int wn   = (wv & 1) * 64;
    const int m0   = blockIdx.y * BM;
    const int n0   = blockIdx.x * BN;

    f32x4 acc[4][4] = {};

    const int arow = t >> 3;
    const int aseg = (t & 7) * 8;
    const int brow = t >> 4;
    const int bcol = (t & 15) * 4;

    for (int k0 = 0; k0 < DIM; k0 += BK) {
        #pragma unroll
        for (int i = 0; i < 4; ++i) {
            const int row = arow + i * 32;
            *(float4*)&As[row][aseg] =
                *(const float4*)&A[(size_t)(m0 + row) * DIM + k0 + aseg];
        }
        #pragma unroll
        for (int i = 0; i < 8; ++i) {
            const int row = brow + i * 16;
            float4 b4 = *(const float4*)&B[(size_t)(n0 + row) * DIM + k0 + bcol];
            ushort4 bh;
            bh.x = f2bf(b4.x); bh.y = f2bf(b4.y);
            bh.z = f2bf(b4.z); bh.w = f2bf(b4.w);
            *(ushort4*)&Bs[row][bcol] = bh;
        }
        __syncthreads();

        #pragma unroll
        for (int ks = 0; ks < BK; ks += 32) {
            const int koff = ks + ((lane >> 4) << 3);
            const int rsel = lane & 15;
            bf16x8 af[4], bf[4];
            #pragma unroll
            for (int i = 0; i < 4; ++i) {
                af[i] = *(const bf16x8*)&As[wm + i * 16 + rsel][koff];
                bf[i] = *(const bf16x8*)&Bs[wn + i * 16 + rsel][koff];
            }
            #pragma unroll
            for (int i = 0; i < 4; ++i)
                #pragma unroll
                for (int j = 0; j < 4; ++j)
                    acc[i][j] = __builtin_amdgcn_mfma_f32_16x16x32_bf16(
                        af[i], bf[j], acc[i][j], 0, 0, 0);
        }
        __syncthreads();
    }

    const int rbase = m0 + wm + ((lane >> 4) << 2);
    const int cbase = n0 + wn + (lane & 15);

    #pragma unroll
    for (int j = 0; j < 4; ++j) {
        const int col = cbase + j * 16;
        const float bv = bias[col];
        #pragma unroll
        for (int i = 0; i < 4; ++i) {
            const int row0 = rbase + i * 16;
            #pragma unroll
            for (int r = 0; r < 4; ++r)
                out[(size_t)(row0 + r) * DIM + col] = acc[i][j][r] + bv;
        }
    }
}

// ---------------------------------------------------------------------------
extern "C" void kernel_launch(void* const* d_in, const int* in_sizes, int n_in,
                              void* d_out, int out_size, void* d_ws, size_t ws_size,
                              hipStream_t stream)
{
    const float* x      = (const float*)d_in[0];   // [4096][768] f32
    const float* qkv_w  = (const float*)d_in[1];   // [2304][768] f32
    const float* proj_w = (const float*)d_in[2];   // [768][768]  f32
    const float* proj_b = (const float*)d_in[3];   // [768]       f32

    const size_t headsz = (size_t)NHEADS * SEQ * HD;     // 3,145,728 elems
    ushort* Qb = (ushort*)d_ws;                          // bf16 [12][4096][64]
    ushort* Kb = Qb + headsz;
    ushort* Vt = Kb + headsz;                            // bf16 [12][64][4096]
    ushort* AO = Vt + headsz;                            // bf16 [4096][768]
    float*  out = (float*)d_out;                         // f32 [4096][768]

    gemm_qkv<<<dim3(3 * DIM / 128, SEQ / 128), 256, 0, stream>>>(
        x, qkv_w, Qb, Kb, Vt);

    flash_mfma<<<dim3(SEQ / 64, NHEADS), 256, 0, stream>>>(Qb, Kb, Vt, AO);

    gemm_proj<<<dim3(DIM / 128, SEQ / 128), 256, 0, stream>>>(
        AO, proj_w, proj_b, out);
}